// Round 2
// baseline (162.478 us; speedup 1.0000x reference)
//
#include <hip/hip_runtime.h>

using u8  = unsigned char;
using u16 = unsigned short;
using u32 = unsigned int;
typedef __attribute__((ext_vector_type(8))) short short8;   // 8 bf16 (MFMA A/B frag)
typedef __attribute__((ext_vector_type(4))) float f32x4;    // MFMA C/D frag

#define QMIN 64    // emit screen: (int)(v*32+0.5) >= 64  <=>  v >= 1.984375
#define SCAP 96    // per-row spill capacity (worst row ~45 expected spills @ 16-slot cells)
#define CMAX 608   // per-row candidate max (m_all <= ~500 at +7sd)
#define RCAP 96    // ambiguous-band capacity (expected ~20, +10sd)
#define BERR 0.045f   // |v_true - v_list| bound (R10 proof implies <=0.031+2e-5)
#define CSLOT 16   // cell slots per (row, 256-col block)

#define AS1 __attribute__((address_space(1)))
#define AS3 __attribute__((address_space(3)))

__device__ __forceinline__ float bf2f(u16 u) {
    union { u32 i; float f; } c; c.i = ((u32)u) << 16; return c.f;
}
__device__ __forceinline__ u16 f2bf(float f) {
    union { float f; u32 i; } c; c.f = f;
    u32 u = c.i + 0x7FFFu + ((c.i >> 16) & 1u);   // RNE; inputs are finite
    return (u16)(u >> 16);
}

// entry: (n << 19) | fixed19, fixed19 = min(floor(v*65536),0x7FFFF) >= 131072
// for valid v >= 1.984 -> 0 is a safe empty sentinel. Saturated -> refine.

// ---------------------------------------------------------------------------
// Kernel 0: FRAGMENT-SWIZZLED bf16 operands + bf16 W_dec + zero spill cnt.
// Swizzle: tile t=(mt*8+kt); lane l holds 8 bf16 at (row=16*mt+(l&15),
// k=32*kt+(l>>4)*8+j) at offset (t*64+l)*8.  (unchanged)
// ---------------------------------------------------------------------------
__global__ __launch_bounds__(256) void prep_convert(const float* __restrict__ x,
                                                    const float* __restrict__ b_dec,
                                                    const float* __restrict__ W_enc,
                                                    const float* __restrict__ W_dec,
                                                    u16* __restrict__ Ap,
                                                    u16* __restrict__ Wb,
                                                    u16* __restrict__ Wd,
                                                    u32* __restrict__ cnt) {
    int i = blockIdx.x * 256 + threadIdx.x;     // grid = 2576 blocks exactly
    if (i < 131072) {                            // A: 256 mt x 8 kt tiles
        int lane = i & 63, t = i >> 6;
        int mt = t >> 3, kt = t & 7;
        int m = mt * 16 + (lane & 15);
        int k = kt * 32 + (lane >> 4) * 8;
        const float* xs = x + (size_t)m * 256 + k;
        const float* bd = b_dec + k;
        u32 o[4];
#pragma unroll
        for (int j = 0; j < 4; j++) {
            u16 lo = f2bf(xs[2*j]   - bd[2*j]);
            u16 hi = f2bf(xs[2*j+1] - bd[2*j+1]);
            o[j] = (u32)lo | ((u32)hi << 16);
        }
        *(uint4*)(Ap + (size_t)i * 8) = make_uint4(o[0], o[1], o[2], o[3]);
    } else if (i < 393216) {                     // W_enc: 512 nt x 8 kt tiles
        int j0 = i - 131072;
        int lane = j0 & 63, t = j0 >> 6;
        int nt = t >> 3, kt = t & 7;
        int n = nt * 16 + (lane & 15);
        int k = kt * 32 + (lane >> 4) * 8;
        const float* ws = W_enc + (size_t)n * 256 + k;
        u32 o[4];
#pragma unroll
        for (int j = 0; j < 4; j++) {
            u16 lo = f2bf(ws[2*j]);
            u16 hi = f2bf(ws[2*j+1]);
            o[j] = (u32)lo | ((u32)hi << 16);
        }
        *(uint4*)(Wb + (size_t)j0 * 8) = make_uint4(o[0], o[1], o[2], o[3]);
    } else if (i < 655360) {                     // W_dec: plain bf16, 8/thread
        int j0 = i - 393216;
        const float* ws = W_dec + (size_t)j0 * 8;
        u32 o[4];
#pragma unroll
        for (int j = 0; j < 4; j++) {
            u16 lo = f2bf(ws[2*j]);
            u16 hi = f2bf(ws[2*j+1]);
            o[j] = (u32)lo | ((u32)hi << 16);
        }
        *(uint4*)(Wd + (size_t)j0 * 8) = make_uint4(o[0], o[1], o[2], o[3]);
    } else {
        int j0 = i - 655360;                     // grid end = 655360+4096
        if (j0 < 4096) cnt[j0] = 0;
    }
}

// ---------------------------------------------------------------------------
// Kernel 1 (v3): BARRIER-FREE K-loop. W strip (256 cols x full K=256) staged
// to LDS ONCE (128 KB, 1 barrier); A-fragments loaded DIRECT to registers
// from the fragment-swizzled Ap (1 coalesced dwordx4 per frag), statically
// double-buffered 1 kt ahead. No per-K-step __syncthreads -> no vmcnt(0)
// drain [R1 lesson: 2-barrier loop at 1 block/CU exposed the full drain,
// 47 us @ 12.7% MfmaUtil]. L2 traffic 96 MB (W 32 + A 64); MFMA floor
// 6.9 us is now binding.
// Grid 256 blocks x 512 thr (8 waves, wave tile 128x64, acc[8][4]=128 VGPR,
// launch_bounds(512,2) -> 256 VGPR cap). Each block: cols bx*256, rows
// mg2*512 as 2 sequential 256-row groups (W LDS reused).
// XCD: id%8=c -> bx in {c*4..c*4+3}: per-XCD L2 = W 512 KB + A 2 MB.
// ---------------------------------------------------------------------------
__global__ __launch_bounds__(512, 2) void encode_gemm(const u16* __restrict__ A,
                                                      const u16* __restrict__ W,
                                                      const float* __restrict__ b_enc,
                                                      u32* __restrict__ cnt,
                                                      u32* __restrict__ seg,
                                                      u32* __restrict__ spill) {
    const int tid  = threadIdx.x;
    const int lane = tid & 63;
    const int wave = tid >> 6;          // 0..7
    const int wm = wave & 1;            // m-half (128 rows)
    const int wn = wave >> 1;           // n-quarter (64 cols)

    const int id  = blockIdx.x;         // 256 blocks
    const int c   = id & 7, j5 = id >> 3;
    const int bx  = c * 4 + (j5 & 3);   // n-block 0..31 (256 cols)
    const int mg2 = j5 >> 2;            // 0..7 (pair of 256-row groups)

    const int ntb = bx * 16;            // block's first n-tile
    const int n0  = bx * 256 + wn * 64;
    const int r15 = lane & 15;

    __shared__ u16 Wl[16 * 8 * 512];    // 128 KB: tile (nt,kt) at (nt*8+kt)*512
    __shared__ u32 cell[256][CSLOT];    // 16 KB per-row candidate cells
    __shared__ u32 l_cnt[256];

    if (tid < 256) l_cnt[tid] = 0;

    // ---- stage W strip once: 128 x 1KB tiles, 16 per wave ------------------
#pragma unroll
    for (int s = 0; s < 16; s++) {
        int slot = wave * 16 + s;               // 0..127
        int nt = slot >> 3, kt = slot & 7;
        const u16* g = W + ((size_t)((ntb + nt) * 8 + kt) * 64 + lane) * 8;
        __builtin_amdgcn_global_load_lds((const AS1 u32*)(const void*)g,
                                         (AS3 u32*)(void*)&Wl[slot * 512],
                                         16, 0, 0);
    }
    __syncthreads();    // drains W stage + covers l_cnt init

    float bias[4];
#pragma unroll
    for (int j = 0; j < 4; j++) bias[j] = b_enc[n0 + j * 16 + r15];

    // per-lane bases: frag (j,kt) of B at wlb + (j*8+kt)*512 (elems)
    const u16* wlb = &Wl[(size_t)(wn * 4) * 8 * 512 + lane * 8];

    for (int g = 0; g < 2; g++) {
        const int m0  = (mg2 * 2 + g) * 256;          // group row base
        const int mtw = (m0 >> 4) + wm * 8;           // wave's first m-tile
        // frag (i,kt) of A at ab + (i*8+kt)*512 (elems)
        const u16* ab = A + ((size_t)mtw * 8 * 64 + lane) * 8;

        f32x4 acc[8][4] = {};
        short8 a0[8], a1[8];
#pragma unroll
        for (int i = 0; i < 8; i++)
            a0[i] = *(const short8*)(ab + (i * 8 + 0) * 512);

#pragma unroll
        for (int kt = 0; kt < 8; kt++) {
            short8* cura = (kt & 1) ? a1 : a0;   // static after unroll
            short8* nxta = (kt & 1) ? a0 : a1;
            if (kt < 7) {
#pragma unroll
                for (int i = 0; i < 8; i++)
                    nxta[i] = *(const short8*)(ab + (i * 8 + kt + 1) * 512);
            }
            short8 b[4];
#pragma unroll
            for (int j = 0; j < 4; j++)
                b[j] = *(const short8*)(wlb + (j * 8 + kt) * 512);
#pragma unroll
            for (int i = 0; i < 8; i++)
#pragma unroll
                for (int j = 0; j < 4; j++)
                    acc[i][j] = __builtin_amdgcn_mfma_f32_16x16x32_bf16(cura[i], b[j], acc[i][j], 0, 0, 0);
        }

        // C/D layout: col(n)=lane&15, row(m)=(lane>>4)*4+reg  [m89-verified]
        // --- emit candidates into per-row LDS cells -------------------------
#pragma unroll
        for (int i = 0; i < 8; i++) {
            int rowl0 = wm * 128 + i * 16 + (lane >> 4) * 4;   // local row
#pragma unroll
            for (int j = 0; j < 4; j++)
#pragma unroll
                for (int rq = 0; rq < 4; rq++) {
                    float v = acc[i][j][rq] + bias[j];
                    if ((int)(v * 32.f + 0.5f) >= QMIN) {
                        int rowl = rowl0 + rq;
                        int n = n0 + j * 16 + r15;
                        int fx = (int)(v * 65536.f);
                        if (fx > 0x7FFFF) fx = 0x7FFFF;   // saturate -> forced refine
                        u32 e = ((u32)n << 19) | (u32)fx;
                        u32 off = atomicAdd(&l_cnt[rowl], 1u);
                        if (off < CSLOT) {
                            cell[rowl][off] = e;
                        } else {                           // rare spill
                            u32 gs = atomicAdd(&cnt[m0 + rowl], 1u);
                            if (gs < SCAP) spill[(size_t)(m0 + rowl) * SCAP + gs] = e;
                        }
                    }
                }
        }
        __syncthreads();

        // --- seg[m0+row][bx][16]: 2 threads/row, 32 B each ------------------
        {
            int row = tid >> 1, half = tid & 1;
            u32 nc = l_cnt[row];
#pragma unroll
            for (int h = 0; h < 2; h++) {
                int base = half * 8 + h * 4;
                uint4 o;
                o.x = (base + 0 < (int)nc) ? cell[row][base + 0] : 0u;
                o.y = (base + 1 < (int)nc) ? cell[row][base + 1] : 0u;
                o.z = (base + 2 < (int)nc) ? cell[row][base + 2] : 0u;
                o.w = (base + 3 < (int)nc) ? cell[row][base + 3] : 0u;
                *(uint4*)(seg + (((size_t)(m0 + row) * 32 + bx) * CSLOT + base)) = o;
            }
        }
        if (g == 0) {                     // reset cells for group 1
            __syncthreads();              // all reads of l_cnt/cell done
            if (tid < 256) l_cnt[tid] = 0;
            __syncthreads();
        }
    }
}

// ---------------------------------------------------------------------------
// Kernel 2: per row — read 512 seg slots (ONE coalesced 2 KB burst, row-major
// layout) (+spills) -> q-hist brackets T -> certain-in (v > Thi+2B, z = v) /
// ambiguous band (fp64 refine, exact ordering) -> decode with bf16 W_dec.
// Exact streaming fallback if screen invalid (never expected).
// XCD row-grouping: 512 contiguous rows per XCD.  (unchanged from R1)
// ---------------------------------------------------------------------------
__global__ __launch_bounds__(256) void select_decode(const u32* __restrict__ cnt,
                                                     const u32* __restrict__ seg,
                                                     const u32* __restrict__ spill,
                                                     const float* __restrict__ x,
                                                     const float* __restrict__ W_enc,
                                                     const float* __restrict__ b_enc,
                                                     const u16* __restrict__ Wd,
                                                     const float* __restrict__ b_dec,
                                                     float* __restrict__ out) {
    const int r    = (blockIdx.x & 7) * 512 + (blockIdx.x >> 3);   // XCD-grouped
    const int tid  = threadIdx.x;
    const int lane = tid & 63;
    const int wave = tid >> 6;
    const int grp  = tid >> 4;     // 16 groups of 16 lanes
    const int l16  = tid & 15;

    __shared__ float s_sae[256];
    __shared__ u32   hist[256];
    __shared__ int   wtot[4];
    __shared__ int   s_t32;
    __shared__ u32   s_m, s_c1, s_namb, s_nref;
    __shared__ int   cidx[CMAX];
    __shared__ float cval[CMAX];
    __shared__ u8    csat[CMAX];
    __shared__ short ridx[RCAP];
    __shared__ float rex[RCAP];
    __shared__ float sel_val[32];
    __shared__ int   sel_idx[32];

    s_sae[tid] = x[(size_t)r * 256 + tid] - b_dec[tid];
    hist[tid] = 0;
    if (tid == 0) { s_t32 = -1; s_m = 0; s_c1 = 0; s_namb = 0; s_nref = 0; }
    if (tid < 32) { sel_val[tid] = 0.f; sel_idx[tid] = 0; }
    __syncthreads();

    auto add_cand = [&](u32 e) {
        int fx = (int)(e & 0x7FFFFu);
        float v = (float)fx * 1.52587890625e-5f;   // /65536
        u32 p = atomicAdd(&s_m, 1u);
        if (p < CMAX) {
            cidx[p] = (int)(e >> 19);
            cval[p] = v;
            csat[p] = (fx == 0x7FFFF);
        }
        int q = (int)(v * 32.f + 0.5f); if (q > 255) q = 255;
        atomicAdd(&hist[q], 1u);
    };
    auto find_t32 = [&]() {
        int c = (int)hist[tid];
        int s = c;
#pragma unroll
        for (int off = 1; off < 64; off <<= 1) {
            int v = __shfl_down(s, off);
            if (lane + off < 64) s += v;
        }
        if (lane == 0) wtot[wave] = s;
        __syncthreads();
        int hisum = 0;
        for (int ww = wave + 1; ww < 4; ww++) hisum += wtot[ww];
        int S = s + hisum;
        if (S >= 32 && (S - c) < 32) s_t32 = tid;   // unique transition bin
        __syncthreads();
    };
    auto exact_col = [&](int col) -> double {
        const float4* wr = (const float4*)(W_enc + (size_t)col * 256 + l16 * 16);
        double s = 0.0;
#pragma unroll
        for (int u = 0; u < 4; u++) {
            float4 wv = wr[u];
            const float* sp = &s_sae[l16 * 16 + u * 4];
            s += (double)wv.x * (double)sp[0] + (double)wv.y * (double)sp[1]
               + (double)wv.z * (double)sp[2] + (double)wv.w * (double)sp[3];
        }
#pragma unroll
        for (int off = 8; off; off >>= 1) s += __shfl_down(s, off, 16);
        return s;
    };

    // --- gather candidates: one coalesced 2 KB burst (512 slots/row) --------
    {
        uint2 ee = *(const uint2*)(seg + (size_t)r * 512 + tid * 2);
        if (ee.x) add_cand(ee.x);
        if (ee.y) add_cand(ee.y);
    }
    const int nsp_all = (int)cnt[r];
    const int nsp = nsp_all < SCAP ? nsp_all : SCAP;
    for (int i = tid; i < nsp; i += 256)
        add_cand(spill[(size_t)r * SCAP + i]);
    __syncthreads();
    const int m = (int)s_m < CMAX ? (int)s_m : CMAX;
    find_t32();

    // t32 >= 67 <=> Tlo-2B >= 1.984 (emit screen) -> non-listed certainly out
    const bool fb_pre = (nsp_all > SCAP) || ((int)s_m > CMAX) || (s_t32 < 67);

    if (!fb_pre) {
        const float Thi = (s_t32 + 0.5f) * 0.03125f;
        const float Tlo = (s_t32 - 0.5f) * 0.03125f;
        for (int i = tid; i < m; i += 256) {
            float v = cval[i];
            if (!csat[i] && v > Thi + 2.f * BERR) {   // certainly in true top-32
                u32 p = atomicAdd(&s_c1, 1u);
                if (p < 32) { sel_val[p] = v; sel_idx[p] = cidx[i]; }
            } else if (csat[i] || v >= Tlo - 2.f * BERR) {  // ambiguous band
                u32 p = atomicAdd(&s_namb, 1u);
                if (p < RCAP) ridx[p] = (short)i;
            }
        }
    }
    __syncthreads();
    const int c1 = (int)s_c1, namb = (int)s_namb;
    const bool fb = fb_pre || (namb > RCAP) || (c1 > 31);

    if (!fb) {
        // --- fp64 refine of ambiguous band: 2 per 16-lane group per pass ----
        for (int t0 = 0; t0 < namb; t0 += 32) {
            int cA = t0 + grp, cB = t0 + grp + 16;
            if (cA < namb) {
                int iA = cidx[ridx[cA]];
                double s = exact_col(iA);
                if (l16 == 0) {
                    float f = (float)(s + (double)b_enc[iA]);
                    rex[cA] = f > 0.f ? f : 0.f;
                }
            }
            if (cB < namb) {
                int iB = cidx[ridx[cB]];
                double s = exact_col(iB);
                if (l16 == 0) {
                    float f = (float)(s + (double)b_enc[iB]);
                    rex[cB] = f > 0.f ? f : 0.f;
                }
            }
        }
        __syncthreads();

        // --- top (32-c1) of band by (exact desc, idx asc) --------------------
        const int need = 32 - c1;
        for (int k = tid; k < namb; k += 256) {
            float vi = rex[k];
            int   ii = cidx[ridx[k]];
            int rank = 0;
            for (int j = 0; j < namb; j++) {
                float vj = rex[j];
                rank += (vj > vi) || (vj == vi && cidx[ridx[j]] < ii);
            }
            if (rank < need) { sel_val[c1 + rank] = vi; sel_idx[c1 + rank] = ii; }
        }
        __syncthreads();
    } else {
        // --- exact streaming fallback over all 8192 cols (never expected) ---
        hist[tid] = 0;
        if (tid == 0) { s_t32 = -1; s_nref = 0; }
        __syncthreads();
        for (int it = 0; it < 512; it++) {
            int col = it * 16 + grp;
            double s = exact_col(col);
            if (l16 == 0) {
                float f = (float)(s + (double)b_enc[col]);
                f = f > 0.f ? f : 0.f;
                int q = (int)(f * 32.f + 0.5f); if (q > 255) q = 255;
                if (q >= 1) atomicAdd(&hist[q], 1u);
            }
        }
        __syncthreads();
        find_t32();
        int qlo = s_t32 >= 3 ? s_t32 - 2 : 1;
        for (int pass = 0; pass < 2; pass++) {
            for (int it = 0; it < 512; it++) {
                int col = it * 16 + grp;
                double s = exact_col(col);
                if (l16 == 0) {
                    float f = (float)(s + (double)b_enc[col]);
                    f = f > 0.f ? f : 0.f;
                    int q = (int)(f * 32.f + 0.5f); if (q > 255) q = 255;
                    if (q >= qlo) {
                        u32 p = atomicAdd(&s_nref, 1u);
                        if (p < CMAX) { cidx[p] = col; cval[p] = f; }
                    }
                }
            }
            __syncthreads();
            if ((int)s_nref <= CMAX) break;
            if (tid == 0) s_nref = 0;
            qlo = s_t32 > 0 ? s_t32 : 1;
            __syncthreads();
        }
        int nf = (int)s_nref; if (nf > CMAX) nf = CMAX;
        for (int k = tid; k < nf; k += 256) {
            float vi = cval[k]; int ii = cidx[k]; int rank = 0;
            for (int j = 0; j < nf; j++)
                rank += (cval[j] > vi) || (cval[j] == vi && cidx[j] < ii);
            if (rank < 32) { sel_val[rank] = vi; sel_idx[rank] = ii; }
        }
        __syncthreads();
    }

    // --- decode: out[r] = b_dec + sum_k z_k * bf16(W_dec)[idx_k] ------------
    u16 wv[32];
#pragma unroll
    for (int k = 0; k < 32; k++)
        wv[k] = Wd[(size_t)sel_idx[k] * 256 + tid];   // 32 independent loads
    float acc = b_dec[tid];
#pragma unroll
    for (int k = 0; k < 32; k++)
        acc += sel_val[k] * bf2f(wv[k]);
    out[(size_t)r * 256 + tid] = acc;
}

// ---------------------------------------------------------------------------
// ws layout (19.5 MB; ws_size is 256 MB per the poison-fill counters):
//   cnt 16 KB | seg 8 MB | spill 1.5 MB | Ap 2 MB | Wb 4 MB | Wd 4 MB
// seg layout row-major: seg[4096][32][16] u32.
// ---------------------------------------------------------------------------
extern "C" void kernel_launch(void* const* d_in, const int* in_sizes, int n_in,
                              void* d_out, int out_size, void* d_ws, size_t ws_size,
                              hipStream_t stream) {
    const float* x     = (const float*)d_in[0];   // [4096,256] f32
    const float* W_enc = (const float*)d_in[1];   // [8192,256] f32
    const float* b_enc = (const float*)d_in[2];   // [8192]     f32
    const float* W_dec = (const float*)d_in[3];   // [8192,256] f32
    const float* b_dec = (const float*)d_in[4];   // [256]      f32
    float* out = (float*)d_out;                   // [4096,256] f32

    u32* cnt   = (u32*)d_ws;                            // 16 KB spill counters
    u32* seg   = cnt + 4096;                            // 8 MB row-major cells
    u32* spill = seg + (size_t)4096 * 32 * CSLOT;       // 1.5 MB spill lists
    u16* Ap    = (u16*)(spill + (size_t)4096 * SCAP);   // 2 MB swizzled bf16(x-b_dec)
    u16* Wb    = Ap + (size_t)4096 * 256;               // 4 MB swizzled bf16(W_enc)
    u16* Wd    = Wb + (size_t)8192 * 256;               // 4 MB bf16(W_dec)

    prep_convert<<<2576, 256, 0, stream>>>(x, b_dec, W_enc, W_dec, Ap, Wb, Wd, cnt);
    encode_gemm<<<256, 512, 0, stream>>>(Ap, Wb, b_enc, cnt, seg, spill);
    select_decode<<<4096, 256, 0, stream>>>(cnt, seg, spill, x, W_enc, b_enc, Wd, b_dec, out);
}

// Round 3
// 145.992 us; speedup vs baseline: 1.1129x; 1.1129x over previous
//
#include <hip/hip_runtime.h>

using u8  = unsigned char;
using u16 = unsigned short;
using u32 = unsigned int;
typedef __attribute__((ext_vector_type(8))) short short8;   // 8 bf16 (MFMA A/B frag)
typedef __attribute__((ext_vector_type(4))) float f32x4;    // MFMA C/D frag

#define QMIN 64    // emit screen: (int)(v*32+0.5) >= 64  <=>  v >= 1.984375
#define SCAP 96    // per-row spill capacity (worst row ~19 expected spills @ 4-slot/32col cells)
#define CMAX 608   // per-row candidate max (m_all <= ~500 at +7sd)
#define RCAP 96    // ambiguous-band capacity (expected ~20, +10sd)
#define BERR 0.045f   // |v_true - v_list| bound (R10 proof implies <=0.031+2e-5)

__device__ __forceinline__ float bf2f(u16 u) {
    union { u32 i; float f; } c; c.i = ((u32)u) << 16; return c.f;
}
__device__ __forceinline__ u16 f2bf(float f) {
    union { float f; u32 i; } c; c.f = f;
    u32 u = c.i + 0x7FFFu + ((c.i >> 16) & 1u);   // RNE; inputs are finite
    return (u16)(u >> 16);
}

// entry: (n << 19) | fixed19, fixed19 = floor(v*65536) (sat 0x7FFFF) >= 130048
// for valid v >= 1.984 -> 0 is a safe empty sentinel. Saturated -> refine.

// ---------------------------------------------------------------------------
// Kernel 0: FRAGMENT-SWIZZLED bf16 operands + bf16 W_dec + zero cnt + zero seg.
// Swizzle: tile t=(mt*8+kt); lane l holds 8 bf16 at (row=16*mt+(l&15),
// k=32*kt+(l>>4)*8+j) at offset (t*64+l)*8.
// ---------------------------------------------------------------------------
__global__ __launch_bounds__(256) void prep_convert(const float* __restrict__ x,
                                                    const float* __restrict__ b_dec,
                                                    const float* __restrict__ W_enc,
                                                    const float* __restrict__ W_dec,
                                                    u16* __restrict__ Ap,
                                                    u16* __restrict__ Wb,
                                                    u16* __restrict__ Wd,
                                                    u32* __restrict__ cnt,
                                                    u32* __restrict__ seg) {
    int i = blockIdx.x * 256 + threadIdx.x;     // grid = 6672 blocks exactly
    if (i < 131072) {                            // A: 256 mt x 8 kt tiles
        int lane = i & 63, t = i >> 6;
        int mt = t >> 3, kt = t & 7;
        int m = mt * 16 + (lane & 15);
        int k = kt * 32 + (lane >> 4) * 8;
        const float* xs = x + (size_t)m * 256 + k;
        const float* bd = b_dec + k;
        u32 o[4];
#pragma unroll
        for (int j = 0; j < 4; j++) {
            u16 lo = f2bf(xs[2*j]   - bd[2*j]);
            u16 hi = f2bf(xs[2*j+1] - bd[2*j+1]);
            o[j] = (u32)lo | ((u32)hi << 16);
        }
        *(uint4*)(Ap + (size_t)i * 8) = make_uint4(o[0], o[1], o[2], o[3]);
    } else if (i < 393216) {                     // W_enc: 512 nt x 8 kt tiles
        int j0 = i - 131072;
        int lane = j0 & 63, t = j0 >> 6;
        int nt = t >> 3, kt = t & 7;
        int n = nt * 16 + (lane & 15);
        int k = kt * 32 + (lane >> 4) * 8;
        const float* ws = W_enc + (size_t)n * 256 + k;
        u32 o[4];
#pragma unroll
        for (int j = 0; j < 4; j++) {
            u16 lo = f2bf(ws[2*j]);
            u16 hi = f2bf(ws[2*j+1]);
            o[j] = (u32)lo | ((u32)hi << 16);
        }
        *(uint4*)(Wb + (size_t)j0 * 8) = make_uint4(o[0], o[1], o[2], o[3]);
    } else if (i < 655360) {                     // W_dec: plain bf16, 8/thread
        int j0 = i - 393216;
        const float* ws = W_dec + (size_t)j0 * 8;
        u32 o[4];
#pragma unroll
        for (int j = 0; j < 4; j++) {
            u16 lo = f2bf(ws[2*j]);
            u16 hi = f2bf(ws[2*j+1]);
            o[j] = (u32)lo | ((u32)hi << 16);
        }
        *(uint4*)(Wd + (size_t)j0 * 8) = make_uint4(o[0], o[1], o[2], o[3]);
    } else if (i < 659456) {                     // zero spill counters
        cnt[i - 655360] = 0;
    } else {                                     // zero seg: 16 MB, uint4 each
        int j1 = i - 659456;                     // 0..1048575
        *(uint4*)(seg + (size_t)j1 * 4) = make_uint4(0u, 0u, 0u, 0u);
    }
}

// ---------------------------------------------------------------------------
// Kernel 1 (v4): ZERO-LDS, ZERO-BARRIER encode GEMM.
// [R1 lesson: 2-barrier 256^2 @1 blk/CU exposed full vmcnt drain, 47us.]
// [R2 lesson: pointer-selected local arrays (cura/nxta) -> scratch spill,
//  VGPR=128 reported vs ~230 needed, 56us. This version: named arrays,
//  static indices ONLY (macros, full unroll).]
// Structure: K=256 is small -> a wave's full B strip (32 cols x 256 K) is
// 16 short8 = 64 VGPR, loaded ONCE. Block = 128 cols x 512 rows, 4 waves
// (one 32-col strip each). Rows stream as 32 chunks of 16 rows: A frags
// direct global->reg (8 coalesced dwordx4), double-buffered one chunk
// ahead (aE/aO, macro-named). 16 MFMA/chunk = ~310 SIMD-cyc window > L2
// latency. Arithmetic: 32 FLOP/B -> 105 B/cyc/CU L2 demand vs ~135 avail.
// VGPR ~165 -> 2 blocks/CU (8 waves), grid 512 = fully resident.
// Emit: per 16-lane group ballot -> rank -> direct seg store
// seg[row][cell=bx*4+wave][slot<4]; overflow -> global spill. seg
// pre-zeroed by prep (empty slots must be 0).
// XCD: id%8=c -> col-blocks c*8..c*8+7 (W slice 512KB) + all A (2MB) = L2 fit.
// ---------------------------------------------------------------------------
#define LOADA(dst, mt) do {                                                    \
    _Pragma("unroll")                                                          \
    for (int kt = 0; kt < 8; kt++)                                             \
        dst[kt] = *(const short8*)(A + ((size_t)((mt) * 8 + kt) * 64 + lane) * 8); \
} while (0)

#define EMIT(vexpr, col, grow, rq) do {                                        \
    float v = (vexpr);                                                         \
    bool pass = ((int)(v * 32.f + 0.5f) >= QMIN);                              \
    unsigned long long mk = __ballot(pass);                                    \
    u32 mg = (u32)(mk >> (g16 * 16)) & 0xFFFFu;                                \
    if (pass) {                                                                \
        int slot = cc[rq] + __popc(mg & ((1u << l16) - 1u));                   \
        int fx = (int)(v * 65536.f); if (fx > 0x7FFFF) fx = 0x7FFFF;           \
        u32 e = ((u32)(col) << 19) | (u32)fx;                                  \
        if (slot < 4) {                                                        \
            seg[((size_t)(grow) * 256 + cellix) * 4 + slot] = e;               \
        } else {                                                               \
            u32 gs = atomicAdd(&cnt[grow], 1u);                                \
            if (gs < SCAP) spill[(size_t)(grow) * SCAP + gs] = e;              \
        }                                                                      \
    }                                                                          \
    cc[rq] += __popc(mg);                                                      \
} while (0)

#define CHUNK(a, ch) do {                                                      \
    f32x4 ac0 = {0.f, 0.f, 0.f, 0.f}, ac1 = {0.f, 0.f, 0.f, 0.f};              \
    _Pragma("unroll")                                                          \
    for (int kt = 0; kt < 8; kt++) {                                           \
        ac0 = __builtin_amdgcn_mfma_f32_16x16x32_bf16(a[kt], b0[kt], ac0, 0, 0, 0); \
        ac1 = __builtin_amdgcn_mfma_f32_16x16x32_bf16(a[kt], b1[kt], ac1, 0, 0, 0); \
    }                                                                          \
    const int rowbase = rg * 512 + (ch) * 16;                                  \
    int cc[4] = {0, 0, 0, 0};                                                  \
    _Pragma("unroll")                                                          \
    for (int rq = 0; rq < 4; rq++) {                                           \
        const int grow = rowbase + g16 * 4 + rq;                               \
        EMIT(ac0[rq] + bias0, n0 + l16,      grow, rq);                        \
        EMIT(ac1[rq] + bias1, n0 + 16 + l16, grow, rq);                        \
    }                                                                          \
} while (0)

__global__ __launch_bounds__(256, 2) void encode_gemm(const u16* __restrict__ A,
                                                      const u16* __restrict__ W,
                                                      const float* __restrict__ b_enc,
                                                      u32* __restrict__ cnt,
                                                      u32* __restrict__ seg,
                                                      u32* __restrict__ spill) {
    const int tid  = threadIdx.x;
    const int lane = tid & 63;
    const int wave = tid >> 6;          // 0..3
    const int g16  = lane >> 4;         // 16-lane row group
    const int l16  = lane & 15;

    const int id = blockIdx.x;          // 512 blocks
    const int c  = id & 7, j = id >> 3; // c = XCD
    const int bx = c * 8 + (j & 7);     // n-block 0..63 (128 cols)
    const int rg = j >> 3;              // row-group 0..7 (512 rows)

    const int n0     = bx * 128 + wave * 32;   // wave's first col
    const int nt0    = bx * 8 + wave * 2;      // wave's first n-tile
    const int cellix = bx * 4 + wave;          // seg cell 0..255
    const int mtb    = rg * 32;                // block's first m-tile

    // ---- B strip in registers, loaded once: 16 x short8 = 64 VGPR ---------
    short8 b0[8], b1[8];
#pragma unroll
    for (int kt = 0; kt < 8; kt++) {
        b0[kt] = *(const short8*)(W + ((size_t)(nt0 * 8 + kt) * 64 + lane) * 8);
        b1[kt] = *(const short8*)(W + ((size_t)((nt0 + 1) * 8 + kt) * 64 + lane) * 8);
    }
    const float bias0 = b_enc[n0 + l16];
    const float bias1 = b_enc[n0 + 16 + l16];

    // ---- A chunk double buffer (named arrays, static indices only) --------
    short8 aE[8], aO[8];
    LOADA(aE, mtb);

    for (int it = 0; it < 16; it++) {
        const int ch = it * 2;
        LOADA(aO, mtb + ch + 1);                           // prefetch odd
        CHUNK(aE, ch);                                     // compute even
        LOADA(aE, mtb + (ch + 2 < 32 ? ch + 2 : 31));      // prefetch next even
        CHUNK(aO, ch + 1);                                 // compute odd
    }
}

// ---------------------------------------------------------------------------
// Kernel 2: per row — read 1024 seg slots (ONE coalesced 4 KB burst,
// row-major seg[4096][256][4]) (+spills) -> q-hist brackets T -> certain-in
// (v > Thi+2B, z = v) / ambiguous band (fp64 refine, exact ordering) ->
// decode with bf16 W_dec. Exact streaming fallback if screen invalid
// (never expected). XCD row-grouping: 512 contiguous rows per XCD.
// ---------------------------------------------------------------------------
__global__ __launch_bounds__(256) void select_decode(const u32* __restrict__ cnt,
                                                     const u32* __restrict__ seg,
                                                     const u32* __restrict__ spill,
                                                     const float* __restrict__ x,
                                                     const float* __restrict__ W_enc,
                                                     const float* __restrict__ b_enc,
                                                     const u16* __restrict__ Wd,
                                                     const float* __restrict__ b_dec,
                                                     float* __restrict__ out) {
    const int r    = (blockIdx.x & 7) * 512 + (blockIdx.x >> 3);   // XCD-grouped
    const int tid  = threadIdx.x;
    const int lane = tid & 63;
    const int wave = tid >> 6;
    const int grp  = tid >> 4;     // 16 groups of 16 lanes
    const int l16  = tid & 15;

    __shared__ float s_sae[256];
    __shared__ u32   hist[256];
    __shared__ int   wtot[4];
    __shared__ int   s_t32;
    __shared__ u32   s_m, s_c1, s_namb, s_nref;
    __shared__ int   cidx[CMAX];
    __shared__ float cval[CMAX];
    __shared__ u8    csat[CMAX];
    __shared__ short ridx[RCAP];
    __shared__ float rex[RCAP];
    __shared__ float sel_val[32];
    __shared__ int   sel_idx[32];

    s_sae[tid] = x[(size_t)r * 256 + tid] - b_dec[tid];
    hist[tid] = 0;
    if (tid == 0) { s_t32 = -1; s_m = 0; s_c1 = 0; s_namb = 0; s_nref = 0; }
    if (tid < 32) { sel_val[tid] = 0.f; sel_idx[tid] = 0; }
    __syncthreads();

    auto add_cand = [&](u32 e) {
        int fx = (int)(e & 0x7FFFFu);
        float v = (float)fx * 1.52587890625e-5f;   // /65536
        u32 p = atomicAdd(&s_m, 1u);
        if (p < CMAX) {
            cidx[p] = (int)(e >> 19);
            cval[p] = v;
            csat[p] = (fx == 0x7FFFF);
        }
        int q = (int)(v * 32.f + 0.5f); if (q > 255) q = 255;
        atomicAdd(&hist[q], 1u);
    };
    auto find_t32 = [&]() {
        int c = (int)hist[tid];
        int s = c;
#pragma unroll
        for (int off = 1; off < 64; off <<= 1) {
            int v = __shfl_down(s, off);
            if (lane + off < 64) s += v;
        }
        if (lane == 0) wtot[wave] = s;
        __syncthreads();
        int hisum = 0;
        for (int ww = wave + 1; ww < 4; ww++) hisum += wtot[ww];
        int S = s + hisum;
        if (S >= 32 && (S - c) < 32) s_t32 = tid;   // unique transition bin
        __syncthreads();
    };
    auto exact_col = [&](int col) -> double {
        const float4* wr = (const float4*)(W_enc + (size_t)col * 256 + l16 * 16);
        double s = 0.0;
#pragma unroll
        for (int u = 0; u < 4; u++) {
            float4 wv = wr[u];
            const float* sp = &s_sae[l16 * 16 + u * 4];
            s += (double)wv.x * (double)sp[0] + (double)wv.y * (double)sp[1]
               + (double)wv.z * (double)sp[2] + (double)wv.w * (double)sp[3];
        }
#pragma unroll
        for (int off = 8; off; off >>= 1) s += __shfl_down(s, off, 16);
        return s;
    };

    // --- gather candidates: one coalesced 4 KB burst (1024 slots/row) -------
    {
        uint4 ee = *(const uint4*)(seg + (size_t)r * 1024 + tid * 4);
        if (ee.x) add_cand(ee.x);
        if (ee.y) add_cand(ee.y);
        if (ee.z) add_cand(ee.z);
        if (ee.w) add_cand(ee.w);
    }
    const int nsp_all = (int)cnt[r];
    const int nsp = nsp_all < SCAP ? nsp_all : SCAP;
    for (int i = tid; i < nsp; i += 256)
        add_cand(spill[(size_t)r * SCAP + i]);
    __syncthreads();
    const int m = (int)s_m < CMAX ? (int)s_m : CMAX;
    find_t32();

    // t32 >= 67 <=> Tlo-2B >= 1.984 (emit screen) -> non-listed certainly out
    const bool fb_pre = (nsp_all > SCAP) || ((int)s_m > CMAX) || (s_t32 < 67);

    if (!fb_pre) {
        const float Thi = (s_t32 + 0.5f) * 0.03125f;
        const float Tlo = (s_t32 - 0.5f) * 0.03125f;
        for (int i = tid; i < m; i += 256) {
            float v = cval[i];
            if (!csat[i] && v > Thi + 2.f * BERR) {   // certainly in true top-32
                u32 p = atomicAdd(&s_c1, 1u);
                if (p < 32) { sel_val[p] = v; sel_idx[p] = cidx[i]; }
            } else if (csat[i] || v >= Tlo - 2.f * BERR) {  // ambiguous band
                u32 p = atomicAdd(&s_namb, 1u);
                if (p < RCAP) ridx[p] = (short)i;
            }
        }
    }
    __syncthreads();
    const int c1 = (int)s_c1, namb = (int)s_namb;
    const bool fb = fb_pre || (namb > RCAP) || (c1 > 31);

    if (!fb) {
        // --- fp64 refine of ambiguous band: 2 per 16-lane group per pass ----
        for (int t0 = 0; t0 < namb; t0 += 32) {
            int cA = t0 + grp, cB = t0 + grp + 16;
            if (cA < namb) {
                int iA = cidx[ridx[cA]];
                double s = exact_col(iA);
                if (l16 == 0) {
                    float f = (float)(s + (double)b_enc[iA]);
                    rex[cA] = f > 0.f ? f : 0.f;
                }
            }
            if (cB < namb) {
                int iB = cidx[ridx[cB]];
                double s = exact_col(iB);
                if (l16 == 0) {
                    float f = (float)(s + (double)b_enc[iB]);
                    rex[cB] = f > 0.f ? f : 0.f;
                }
            }
        }
        __syncthreads();

        // --- top (32-c1) of band by (exact desc, idx asc) --------------------
        const int need = 32 - c1;
        for (int k = tid; k < namb; k += 256) {
            float vi = rex[k];
            int   ii = cidx[ridx[k]];
            int rank = 0;
            for (int j = 0; j < namb; j++) {
                float vj = rex[j];
                rank += (vj > vi) || (vj == vi && cidx[ridx[j]] < ii);
            }
            if (rank < need) { sel_val[c1 + rank] = vi; sel_idx[c1 + rank] = ii; }
        }
        __syncthreads();
    } else {
        // --- exact streaming fallback over all 8192 cols (never expected) ---
        hist[tid] = 0;
        if (tid == 0) { s_t32 = -1; s_nref = 0; }
        __syncthreads();
        for (int it = 0; it < 512; it++) {
            int col = it * 16 + grp;
            double s = exact_col(col);
            if (l16 == 0) {
                float f = (float)(s + (double)b_enc[col]);
                f = f > 0.f ? f : 0.f;
                int q = (int)(f * 32.f + 0.5f); if (q > 255) q = 255;
                if (q >= 1) atomicAdd(&hist[q], 1u);
            }
        }
        __syncthreads();
        find_t32();
        int qlo = s_t32 >= 3 ? s_t32 - 2 : 1;
        for (int pass = 0; pass < 2; pass++) {
            for (int it = 0; it < 512; it++) {
                int col = it * 16 + grp;
                double s = exact_col(col);
                if (l16 == 0) {
                    float f = (float)(s + (double)b_enc[col]);
                    f = f > 0.f ? f : 0.f;
                    int q = (int)(f * 32.f + 0.5f); if (q > 255) q = 255;
                    if (q >= qlo) {
                        u32 p = atomicAdd(&s_nref, 1u);
                        if (p < CMAX) { cidx[p] = col; cval[p] = f; }
                    }
                }
            }
            __syncthreads();
            if ((int)s_nref <= CMAX) break;
            if (tid == 0) s_nref = 0;
            qlo = s_t32 > 0 ? s_t32 : 1;
            __syncthreads();
        }
        int nf = (int)s_nref; if (nf > CMAX) nf = CMAX;
        for (int k = tid; k < nf; k += 256) {
            float vi = cval[k]; int ii = cidx[k]; int rank = 0;
            for (int j = 0; j < nf; j++)
                rank += (cval[j] > vi) || (cval[j] == vi && cidx[j] < ii);
            if (rank < 32) { sel_val[rank] = vi; sel_idx[rank] = ii; }
        }
        __syncthreads();
    }

    // --- decode: out[r] = b_dec + sum_k z_k * bf16(W_dec)[idx_k] ------------
    u16 wv[32];
#pragma unroll
    for (int k = 0; k < 32; k++)
        wv[k] = Wd[(size_t)sel_idx[k] * 256 + tid];   // 32 independent loads
    float acc = b_dec[tid];
#pragma unroll
    for (int k = 0; k < 32; k++)
        acc += sel_val[k] * bf2f(wv[k]);
    out[(size_t)r * 256 + tid] = acc;
}

// ---------------------------------------------------------------------------
// ws layout (~27.5 MB; ws_size is 256 MB):
//   cnt 16 KB | seg 16 MB (seg[4096][256][4] u32, pre-zeroed by prep) |
//   spill 1.5 MB | Ap 2 MB | Wb 4 MB | Wd 4 MB
// ---------------------------------------------------------------------------
extern "C" void kernel_launch(void* const* d_in, const int* in_sizes, int n_in,
                              void* d_out, int out_size, void* d_ws, size_t ws_size,
                              hipStream_t stream) {
    const float* x     = (const float*)d_in[0];   // [4096,256] f32
    const float* W_enc = (const float*)d_in[1];   // [8192,256] f32
    const float* b_enc = (const float*)d_in[2];   // [8192]     f32
    const float* W_dec = (const float*)d_in[3];   // [8192,256] f32
    const float* b_dec = (const float*)d_in[4];   // [256]      f32
    float* out = (float*)d_out;                   // [4096,256] f32

    u32* cnt   = (u32*)d_ws;                            // 16 KB spill counters
    u32* seg   = cnt + 4096;                            // 16 MB candidate slots
    u32* spill = seg + (size_t)4096 * 1024;             // 1.5 MB spill lists
    u16* Ap    = (u16*)(spill + (size_t)4096 * SCAP);   // 2 MB swizzled bf16(x-b_dec)
    u16* Wb    = Ap + (size_t)4096 * 256;               // 4 MB swizzled bf16(W_enc)
    u16* Wd    = Wb + (size_t)8192 * 256;               // 4 MB bf16(W_dec)

    prep_convert<<<6672, 256, 0, stream>>>(x, b_dec, W_enc, W_dec, Ap, Wb, Wd, cnt, seg);
    encode_gemm<<<512, 256, 0, stream>>>(Ap, Wb, b_enc, cnt, seg, spill);
    select_decode<<<4096, 256, 0, stream>>>(cnt, seg, spill, x, W_enc, b_enc, Wd, b_dec, out);
}

// Round 4
// 145.540 us; speedup vs baseline: 1.1164x; 1.0031x over previous
//
#include <hip/hip_runtime.h>

using u8  = unsigned char;
using u16 = unsigned short;
using u32 = unsigned int;
typedef __attribute__((ext_vector_type(8))) short short8;   // 8 bf16 (MFMA A/B frag)
typedef __attribute__((ext_vector_type(4))) float f32x4;    // MFMA C/D frag

#define QMIN 64    // emit screen: (int)(v*32+0.5) >= 64  <=>  v >= 1.984375
#define SCAP 96    // per-row spill capacity (expected ~0.25 spills/row @ 4-slot/32col cells)
#define CMAX 608   // per-row candidate max (m_all <= ~500 at +7sd)
#define RCAP 96    // ambiguous-band capacity (expected ~20, +10sd)
#define BERR 0.045f   // |v_true - v_list| bound (R10 proof implies <=0.031+2e-5)

__device__ __forceinline__ float bf2f(u16 u) {
    union { u32 i; float f; } c; c.i = ((u32)u) << 16; return c.f;
}
__device__ __forceinline__ u16 f2bf(float f) {
    union { float f; u32 i; } c; c.f = f;
    u32 u = c.i + 0x7FFFu + ((c.i >> 16) & 1u);   // RNE; inputs are finite
    return (u16)(u >> 16);
}

// entry: (n << 19) | fixed19, fixed19 = floor(v*65536) (sat 0x7FFFF) >= 130048
// for valid v >= 1.984 -> 0 is a safe empty sentinel. Saturated -> refine.

// ---------------------------------------------------------------------------
// Kernel 0: FRAGMENT-SWIZZLED bf16 operands + bf16 W_dec + zero cnt + zero seg.
// Swizzle: tile t=(mt*8+kt); lane l holds 8 bf16 at (row=16*mt+(l&15),
// k=32*kt+(l>>4)*8+j) at offset (t*64+l)*8.  (unchanged)
// ---------------------------------------------------------------------------
__global__ __launch_bounds__(256) void prep_convert(const float* __restrict__ x,
                                                    const float* __restrict__ b_dec,
                                                    const float* __restrict__ W_enc,
                                                    const float* __restrict__ W_dec,
                                                    u16* __restrict__ Ap,
                                                    u16* __restrict__ Wb,
                                                    u16* __restrict__ Wd,
                                                    u32* __restrict__ cnt,
                                                    u32* __restrict__ seg) {
    int i = blockIdx.x * 256 + threadIdx.x;     // grid = 6672 blocks exactly
    if (i < 131072) {                            // A: 256 mt x 8 kt tiles
        int lane = i & 63, t = i >> 6;
        int mt = t >> 3, kt = t & 7;
        int m = mt * 16 + (lane & 15);
        int k = kt * 32 + (lane >> 4) * 8;
        const float* xs = x + (size_t)m * 256 + k;
        const float* bd = b_dec + k;
        u32 o[4];
#pragma unroll
        for (int j = 0; j < 4; j++) {
            u16 lo = f2bf(xs[2*j]   - bd[2*j]);
            u16 hi = f2bf(xs[2*j+1] - bd[2*j+1]);
            o[j] = (u32)lo | ((u32)hi << 16);
        }
        *(uint4*)(Ap + (size_t)i * 8) = make_uint4(o[0], o[1], o[2], o[3]);
    } else if (i < 393216) {                     // W_enc: 512 nt x 8 kt tiles
        int j0 = i - 131072;
        int lane = j0 & 63, t = j0 >> 6;
        int nt = t >> 3, kt = t & 7;
        int n = nt * 16 + (lane & 15);
        int k = kt * 32 + (lane >> 4) * 8;
        const float* ws = W_enc + (size_t)n * 256 + k;
        u32 o[4];
#pragma unroll
        for (int j = 0; j < 4; j++) {
            u16 lo = f2bf(ws[2*j]);
            u16 hi = f2bf(ws[2*j+1]);
            o[j] = (u32)lo | ((u32)hi << 16);
        }
        *(uint4*)(Wb + (size_t)j0 * 8) = make_uint4(o[0], o[1], o[2], o[3]);
    } else if (i < 655360) {                     // W_dec: plain bf16, 8/thread
        int j0 = i - 393216;
        const float* ws = W_dec + (size_t)j0 * 8;
        u32 o[4];
#pragma unroll
        for (int j = 0; j < 4; j++) {
            u16 lo = f2bf(ws[2*j]);
            u16 hi = f2bf(ws[2*j+1]);
            o[j] = (u32)lo | ((u32)hi << 16);
        }
        *(uint4*)(Wd + (size_t)j0 * 8) = make_uint4(o[0], o[1], o[2], o[3]);
    } else if (i < 659456) {                     // zero spill counters
        cnt[i - 655360] = 0;
    } else {                                     // zero seg: 16 MB, uint4 each
        int j1 = i - 659456;                     // 0..1048575
        *(uint4*)(seg + (size_t)j1 * 4) = make_uint4(0u, 0u, 0u, 0u);
    }
}

// ---------------------------------------------------------------------------
// Kernel 1 (v5): ZERO-LDS, ZERO-BARRIER encode GEMM, L2-traffic-minimized.
// [R1 lesson: barrier drain @1 blk/CU = 47us. R2 lesson: pointer-selected
//  local arrays -> scratch = 56us. R3 lesson (v4): structure works (~36us)
//  but L2 bytes bound it: BN=128 blocks pull A 64x with only 4-way L1 share.]
// v5 = v4 geometry change ONLY: BN 128->256 (8 waves/block, 512 thr),
// grid 512->256 (1 block/CU). L2 traffic = A*(8192/256) + W*(4096/512)
// = 64 + 32 = 96 MB (vs ~160-500 effective in v4). A-chunk (8 KB) shared
// by 8 waves via L1. B strip (32 cols x 256 K = 16 short8 = 64 VGPR)
// register-resident, loaded once. Rows stream as 32 chunks of 16: A frags
// direct global->reg (8 coalesced dwordx4), double-buffered (named arrays,
// static indices). Emit: per 16-lane-group ballot -> rank -> direct
// seg[row][cell=bx*8+wave][slot<4] store; overflow -> global spill.
// VGPR ~170 (launch_bounds(512,2) -> 256 cap). No LDS, no barriers.
// XCD: id%8=c -> bx in {c*4..c*4+3}: per-XCD L2 = W 512KB + A 2MB < 4MB.
// ---------------------------------------------------------------------------
#define LOADA(dst, mt) do {                                                    \
    _Pragma("unroll")                                                          \
    for (int kt = 0; kt < 8; kt++)                                             \
        dst[kt] = *(const short8*)(A + ((size_t)((mt) * 8 + kt) * 64 + lane) * 8); \
} while (0)

#define EMIT(vexpr, col, grow, rq) do {                                        \
    float v = (vexpr);                                                         \
    bool pass = ((int)(v * 32.f + 0.5f) >= QMIN);                              \
    unsigned long long mk = __ballot(pass);                                    \
    u32 mg = (u32)(mk >> (g16 * 16)) & 0xFFFFu;                                \
    if (pass) {                                                                \
        int slot = cc[rq] + __popc(mg & ((1u << l16) - 1u));                   \
        int fx = (int)(v * 65536.f); if (fx > 0x7FFFF) fx = 0x7FFFF;           \
        u32 e = ((u32)(col) << 19) | (u32)fx;                                  \
        if (slot < 4) {                                                        \
            seg[((size_t)(grow) * 256 + cellix) * 4 + slot] = e;               \
        } else {                                                               \
            u32 gs = atomicAdd(&cnt[grow], 1u);                                \
            if (gs < SCAP) spill[(size_t)(grow) * SCAP + gs] = e;              \
        }                                                                      \
    }                                                                          \
    cc[rq] += __popc(mg);                                                      \
} while (0)

#define CHUNK(a, ch) do {                                                      \
    f32x4 ac0 = {0.f, 0.f, 0.f, 0.f}, ac1 = {0.f, 0.f, 0.f, 0.f};              \
    _Pragma("unroll")                                                          \
    for (int kt = 0; kt < 8; kt++) {                                           \
        ac0 = __builtin_amdgcn_mfma_f32_16x16x32_bf16(a[kt], b0[kt], ac0, 0, 0, 0); \
        ac1 = __builtin_amdgcn_mfma_f32_16x16x32_bf16(a[kt], b1[kt], ac1, 0, 0, 0); \
    }                                                                          \
    const int rowbase = rg * 512 + (ch) * 16;                                  \
    int cc[4] = {0, 0, 0, 0};                                                  \
    _Pragma("unroll")                                                          \
    for (int rq = 0; rq < 4; rq++) {                                           \
        const int grow = rowbase + g16 * 4 + rq;                               \
        EMIT(ac0[rq] + bias0, n0 + l16,      grow, rq);                        \
        EMIT(ac1[rq] + bias1, n0 + 16 + l16, grow, rq);                        \
    }                                                                          \
} while (0)

__global__ __launch_bounds__(512, 2) void encode_gemm(const u16* __restrict__ A,
                                                      const u16* __restrict__ W,
                                                      const float* __restrict__ b_enc,
                                                      u32* __restrict__ cnt,
                                                      u32* __restrict__ seg,
                                                      u32* __restrict__ spill) {
    const int tid  = threadIdx.x;
    const int lane = tid & 63;
    const int wave = tid >> 6;          // 0..7
    const int g16  = lane >> 4;         // 16-lane row group
    const int l16  = lane & 15;

    const int id = blockIdx.x;          // 256 blocks (1 per CU)
    const int c  = id & 7, j = id >> 3; // c = XCD, j = 0..31
    const int bx = c * 4 + (j & 3);     // n-block 0..31 (256 cols)
    const int rg = j >> 2;              // row-group 0..7 (512 rows)

    const int n0     = bx * 256 + wave * 32;   // wave's first col
    const int nt0    = bx * 16 + wave * 2;     // wave's first n-tile
    const int cellix = bx * 8 + wave;          // seg cell 0..255
    const int mtb    = rg * 32;                // block's first m-tile

    // ---- B strip in registers, loaded once: 16 x short8 = 64 VGPR ---------
    short8 b0[8], b1[8];
#pragma unroll
    for (int kt = 0; kt < 8; kt++) {
        b0[kt] = *(const short8*)(W + ((size_t)(nt0 * 8 + kt) * 64 + lane) * 8);
        b1[kt] = *(const short8*)(W + ((size_t)((nt0 + 1) * 8 + kt) * 64 + lane) * 8);
    }
    const float bias0 = b_enc[n0 + l16];
    const float bias1 = b_enc[n0 + 16 + l16];

    // ---- A chunk double buffer (named arrays, static indices only) --------
    short8 aE[8], aO[8];
    LOADA(aE, mtb);

    for (int it = 0; it < 16; it++) {
        const int ch = it * 2;
        LOADA(aO, mtb + ch + 1);                           // prefetch odd
        CHUNK(aE, ch);                                     // compute even
        LOADA(aE, mtb + (ch + 2 < 32 ? ch + 2 : 31));      // prefetch next even
        CHUNK(aO, ch + 1);                                 // compute odd
    }
}

// ---------------------------------------------------------------------------
// Kernel 2: per row — read 1024 seg slots (ONE coalesced 4 KB burst,
// row-major seg[4096][256][4]) (+spills) -> q-hist brackets T -> certain-in
// (v > Thi+2B, z = v) / ambiguous band (fp64 refine, exact ordering) ->
// decode with bf16 W_dec. Exact streaming fallback if screen invalid
// (never expected). XCD row-grouping: 512 contiguous rows per XCD.
// (unchanged from R3)
// ---------------------------------------------------------------------------
__global__ __launch_bounds__(256) void select_decode(const u32* __restrict__ cnt,
                                                     const u32* __restrict__ seg,
                                                     const u32* __restrict__ spill,
                                                     const float* __restrict__ x,
                                                     const float* __restrict__ W_enc,
                                                     const float* __restrict__ b_enc,
                                                     const u16* __restrict__ Wd,
                                                     const float* __restrict__ b_dec,
                                                     float* __restrict__ out) {
    const int r    = (blockIdx.x & 7) * 512 + (blockIdx.x >> 3);   // XCD-grouped
    const int tid  = threadIdx.x;
    const int lane = tid & 63;
    const int wave = tid >> 6;
    const int grp  = tid >> 4;     // 16 groups of 16 lanes
    const int l16  = tid & 15;

    __shared__ float s_sae[256];
    __shared__ u32   hist[256];
    __shared__ int   wtot[4];
    __shared__ int   s_t32;
    __shared__ u32   s_m, s_c1, s_namb, s_nref;
    __shared__ int   cidx[CMAX];
    __shared__ float cval[CMAX];
    __shared__ u8    csat[CMAX];
    __shared__ short ridx[RCAP];
    __shared__ float rex[RCAP];
    __shared__ float sel_val[32];
    __shared__ int   sel_idx[32];

    s_sae[tid] = x[(size_t)r * 256 + tid] - b_dec[tid];
    hist[tid] = 0;
    if (tid == 0) { s_t32 = -1; s_m = 0; s_c1 = 0; s_namb = 0; s_nref = 0; }
    if (tid < 32) { sel_val[tid] = 0.f; sel_idx[tid] = 0; }
    __syncthreads();

    auto add_cand = [&](u32 e) {
        int fx = (int)(e & 0x7FFFFu);
        float v = (float)fx * 1.52587890625e-5f;   // /65536
        u32 p = atomicAdd(&s_m, 1u);
        if (p < CMAX) {
            cidx[p] = (int)(e >> 19);
            cval[p] = v;
            csat[p] = (fx == 0x7FFFF);
        }
        int q = (int)(v * 32.f + 0.5f); if (q > 255) q = 255;
        atomicAdd(&hist[q], 1u);
    };
    auto find_t32 = [&]() {
        int c = (int)hist[tid];
        int s = c;
#pragma unroll
        for (int off = 1; off < 64; off <<= 1) {
            int v = __shfl_down(s, off);
            if (lane + off < 64) s += v;
        }
        if (lane == 0) wtot[wave] = s;
        __syncthreads();
        int hisum = 0;
        for (int ww = wave + 1; ww < 4; ww++) hisum += wtot[ww];
        int S = s + hisum;
        if (S >= 32 && (S - c) < 32) s_t32 = tid;   // unique transition bin
        __syncthreads();
    };
    auto exact_col = [&](int col) -> double {
        const float4* wr = (const float4*)(W_enc + (size_t)col * 256 + l16 * 16);
        double s = 0.0;
#pragma unroll
        for (int u = 0; u < 4; u++) {
            float4 wv = wr[u];
            const float* sp = &s_sae[l16 * 16 + u * 4];
            s += (double)wv.x * (double)sp[0] + (double)wv.y * (double)sp[1]
               + (double)wv.z * (double)sp[2] + (double)wv.w * (double)sp[3];
        }
#pragma unroll
        for (int off = 8; off; off >>= 1) s += __shfl_down(s, off, 16);
        return s;
    };

    // --- gather candidates: one coalesced 4 KB burst (1024 slots/row) -------
    {
        uint4 ee = *(const uint4*)(seg + (size_t)r * 1024 + tid * 4);
        if (ee.x) add_cand(ee.x);
        if (ee.y) add_cand(ee.y);
        if (ee.z) add_cand(ee.z);
        if (ee.w) add_cand(ee.w);
    }
    const int nsp_all = (int)cnt[r];
    const int nsp = nsp_all < SCAP ? nsp_all : SCAP;
    for (int i = tid; i < nsp; i += 256)
        add_cand(spill[(size_t)r * SCAP + i]);
    __syncthreads();
    const int m = (int)s_m < CMAX ? (int)s_m : CMAX;
    find_t32();

    // t32 >= 67 <=> Tlo-2B >= 1.984 (emit screen) -> non-listed certainly out
    const bool fb_pre = (nsp_all > SCAP) || ((int)s_m > CMAX) || (s_t32 < 67);

    if (!fb_pre) {
        const float Thi = (s_t32 + 0.5f) * 0.03125f;
        const float Tlo = (s_t32 - 0.5f) * 0.03125f;
        for (int i = tid; i < m; i += 256) {
            float v = cval[i];
            if (!csat[i] && v > Thi + 2.f * BERR) {   // certainly in true top-32
                u32 p = atomicAdd(&s_c1, 1u);
                if (p < 32) { sel_val[p] = v; sel_idx[p] = cidx[i]; }
            } else if (csat[i] || v >= Tlo - 2.f * BERR) {  // ambiguous band
                u32 p = atomicAdd(&s_namb, 1u);
                if (p < RCAP) ridx[p] = (short)i;
            }
        }
    }
    __syncthreads();
    const int c1 = (int)s_c1, namb = (int)s_namb;
    const bool fb = fb_pre || (namb > RCAP) || (c1 > 31);

    if (!fb) {
        // --- fp64 refine of ambiguous band: 2 per 16-lane group per pass ----
        for (int t0 = 0; t0 < namb; t0 += 32) {
            int cA = t0 + grp, cB = t0 + grp + 16;
            if (cA < namb) {
                int iA = cidx[ridx[cA]];
                double s = exact_col(iA);
                if (l16 == 0) {
                    float f = (float)(s + (double)b_enc[iA]);
                    rex[cA] = f > 0.f ? f : 0.f;
                }
            }
            if (cB < namb) {
                int iB = cidx[ridx[cB]];
                double s = exact_col(iB);
                if (l16 == 0) {
                    float f = (float)(s + (double)b_enc[iB]);
                    rex[cB] = f > 0.f ? f : 0.f;
                }
            }
        }
        __syncthreads();

        // --- top (32-c1) of band by (exact desc, idx asc) --------------------
        const int need = 32 - c1;
        for (int k = tid; k < namb; k += 256) {
            float vi = rex[k];
            int   ii = cidx[ridx[k]];
            int rank = 0;
            for (int j = 0; j < namb; j++) {
                float vj = rex[j];
                rank += (vj > vi) || (vj == vi && cidx[ridx[j]] < ii);
            }
            if (rank < need) { sel_val[c1 + rank] = vi; sel_idx[c1 + rank] = ii; }
        }
        __syncthreads();
    } else {
        // --- exact streaming fallback over all 8192 cols (never expected) ---
        hist[tid] = 0;
        if (tid == 0) { s_t32 = -1; s_nref = 0; }
        __syncthreads();
        for (int it = 0; it < 512; it++) {
            int col = it * 16 + grp;
            double s = exact_col(col);
            if (l16 == 0) {
                float f = (float)(s + (double)b_enc[col]);
                f = f > 0.f ? f : 0.f;
                int q = (int)(f * 32.f + 0.5f); if (q > 255) q = 255;
                if (q >= 1) atomicAdd(&hist[q], 1u);
            }
        }
        __syncthreads();
        find_t32();
        int qlo = s_t32 >= 3 ? s_t32 - 2 : 1;
        for (int pass = 0; pass < 2; pass++) {
            for (int it = 0; it < 512; it++) {
                int col = it * 16 + grp;
                double s = exact_col(col);
                if (l16 == 0) {
                    float f = (float)(s + (double)b_enc[col]);
                    f = f > 0.f ? f : 0.f;
                    int q = (int)(f * 32.f + 0.5f); if (q > 255) q = 255;
                    if (q >= qlo) {
                        u32 p = atomicAdd(&s_nref, 1u);
                        if (p < CMAX) { cidx[p] = col; cval[p] = f; }
                    }
                }
            }
            __syncthreads();
            if ((int)s_nref <= CMAX) break;
            if (tid == 0) s_nref = 0;
            qlo = s_t32 > 0 ? s_t32 : 1;
            __syncthreads();
        }
        int nf = (int)s_nref; if (nf > CMAX) nf = CMAX;
        for (int k = tid; k < nf; k += 256) {
            float vi = cval[k]; int ii = cidx[k]; int rank = 0;
            for (int j = 0; j < nf; j++)
                rank += (cval[j] > vi) || (cval[j] == vi && cidx[j] < ii);
            if (rank < 32) { sel_val[rank] = vi; sel_idx[rank] = ii; }
        }
        __syncthreads();
    }

    // --- decode: out[r] = b_dec + sum_k z_k * bf16(W_dec)[idx_k] ------------
    u16 wv[32];
#pragma unroll
    for (int k = 0; k < 32; k++)
        wv[k] = Wd[(size_t)sel_idx[k] * 256 + tid];   // 32 independent loads
    float acc = b_dec[tid];
#pragma unroll
    for (int k = 0; k < 32; k++)
        acc += sel_val[k] * bf2f(wv[k]);
    out[(size_t)r * 256 + tid] = acc;
}

// ---------------------------------------------------------------------------
// ws layout (~27.5 MB; ws_size is 256 MB):
//   cnt 16 KB | seg 16 MB (seg[4096][256][4] u32, pre-zeroed by prep) |
//   spill 1.5 MB | Ap 2 MB | Wb 4 MB | Wd 4 MB
// ---------------------------------------------------------------------------
extern "C" void kernel_launch(void* const* d_in, const int* in_sizes, int n_in,
                              void* d_out, int out_size, void* d_ws, size_t ws_size,
                              hipStream_t stream) {
    const float* x     = (const float*)d_in[0];   // [4096,256] f32
    const float* W_enc = (const float*)d_in[1];   // [8192,256] f32
    const float* b_enc = (const float*)d_in[2];   // [8192]     f32
    const float* W_dec = (const float*)d_in[3];   // [8192,256] f32
    const float* b_dec = (const float*)d_in[4];   // [256]      f32
    float* out = (float*)d_out;                   // [4096,256] f32

    u32* cnt   = (u32*)d_ws;                            // 16 KB spill counters
    u32* seg   = cnt + 4096;                            // 16 MB candidate slots
    u32* spill = seg + (size_t)4096 * 1024;             // 1.5 MB spill lists
    u16* Ap    = (u16*)(spill + (size_t)4096 * SCAP);   // 2 MB swizzled bf16(x-b_dec)
    u16* Wb    = Ap + (size_t)4096 * 256;               // 4 MB swizzled bf16(W_enc)
    u16* Wd    = Wb + (size_t)8192 * 256;               // 4 MB bf16(W_dec)

    prep_convert<<<6672, 256, 0, stream>>>(x, b_dec, W_enc, W_dec, Ap, Wb, Wd, cnt, seg);
    encode_gemm<<<256, 512, 0, stream>>>(Ap, Wb, b_enc, cnt, seg, spill);
    select_decode<<<4096, 256, 0, stream>>>(cnt, seg, spill, x, W_enc, b_enc, Wd, b_dec, out);
}